// Round 1
// baseline (816.691 us; speedup 1.0000x reference)
//
#include <hip/hip_runtime.h>
#include <hip/hip_bf16.h>
#include <stdint.h>

// Problem constants (B,T,D,M) = (4,4096,2048,512)
#define BB 4
#define TT 4096
#define DDIM 2048
#define MDIM 512
#define NROWS (BB * TT)          // 16384
#define KCAT (DDIM + MDIM)       // 2560
#define CHUNK 64
#define NCH (TT / CHUNK)         // 64

typedef __attribute__((ext_vector_type(8))) short bf16x8;
typedef __attribute__((ext_vector_type(4))) float f32x4;

__device__ __forceinline__ unsigned short f2bf(float f) {
  unsigned u = __float_as_uint(f);
  return (unsigned short)((u + 0x7fffu + ((u >> 16) & 1u)) >> 16);  // RNE
}
__device__ __forceinline__ float sigm(float x) { return 1.0f / (1.0f + expf(-x)); }

__device__ __forceinline__ void gload16(const void* g, void* l) {
  __builtin_amdgcn_global_load_lds(
      (const __attribute__((address_space(1))) unsigned int*)g,
      (__attribute__((address_space(3))) unsigned int*)l, 16, 0, 0);
}

// ---------------- conversions ----------------
// x [16384,2048] f32 -> combined[:, :2048] bf16 (row stride KCAT)
__global__ void cvt_x_kernel(const float* __restrict__ x, unsigned short* __restrict__ comb) {
  size_t i = (size_t)blockIdx.x * 256 + threadIdx.x;  // one float4 per thread
  size_t row = i >> 9;           // 512 float4 per row
  size_t c = (i & 511) << 2;
  float4 f = ((const float4*)x)[i];
  ushort4 o;
  o.x = f2bf(f.x); o.y = f2bf(f.y); o.z = f2bf(f.z); o.w = f2bf(f.w);
  *((ushort4*)(comb + row * KCAT + c)) = o;
}

__global__ void cvt_w_kernel(const float* __restrict__ src, unsigned short* __restrict__ dst, long n4) {
  long i = (long)blockIdx.x * 256 + threadIdx.x;
  if (i >= n4) return;
  float4 f = ((const float4*)src)[i];
  ushort4 o;
  o.x = f2bf(f.x); o.y = f2bf(f.y); o.z = f2bf(f.z); o.w = f2bf(f.w);
  ((ushort4*)dst)[i] = o;
}

// ---------------- GEMM: out[r,c] = sum_k A[r,k]*B[c,k] (+bias, +x residual) ----------------
// 128x128 tile, BK=32, 4 waves (2x2 of 64x64), 16x16x32 bf16 MFMA.
// LDS tiles stored k-block-major: [BK/8=4][128 rows][8 k] bf16 -> staging is linear
// (global_load_lds-compatible) AND ds_read_b128 fragment reads are 2-way-conflict-free.
template<int EPI>
__global__ __launch_bounds__(256, 3) void gemm_bf16_kernel(
    const unsigned short* __restrict__ A, long lda,  // [rows, K] row-major, stride lda
    const unsigned short* __restrict__ B, long K,    // [N, K] row-major (B^T form)
    float* __restrict__ out, long ldo,
    const float* __restrict__ bias,                  // [N]
    const float* __restrict__ xres,                  // EPI==1: residual [rows, ldo]
    int nrb)                                         // number of row blocks
{
  __shared__ __align__(16) unsigned char ldsA[2][8192];
  __shared__ __align__(16) unsigned char ldsB[2][8192];

  const int tid = threadIdx.x;
  const int nwg = gridDim.x;
  int lin = blockIdx.x;
  // bijective XCD swizzle (all our grids are multiples of 8)
  lin = (lin & 7) * (nwg >> 3) + (lin >> 3);
  const long row0 = (long)(lin % nrb) * 128;
  const long col0 = (long)(lin / nrb) * 128;

  const int lane = tid & 63;
  const int wave = tid >> 6;
  const int wr = (wave >> 1) * 64;
  const int wc = (wave & 1) * 64;

  // staging: per issue j, LDS linear byte off = j*4096 + tid*16
  //   -> kblock = j*2 + (tid>>7), row = tid&127, k0 = kblock*8
  const int srow = tid & 127;
  const int skb = tid >> 7;  // 0..1
  const unsigned short* aS = A + (row0 + srow) * lda + skb * 8;
  const unsigned short* bS = B + (col0 + srow) * K + skb * 8;
  const int ldst = tid * 16;

  f32x4 acc[4][4];
#pragma unroll
  for (int i = 0; i < 4; ++i)
#pragma unroll
    for (int j = 0; j < 4; ++j)
      acc[i][j] = {0.f, 0.f, 0.f, 0.f};

  // fragment LDS byte offsets: [kblock=lane>>4][row][8] -> (lane>>4)*2048 + row*16
  int aOff[4], bOff[4];
#pragma unroll
  for (int i = 0; i < 4; ++i) {
    aOff[i] = ((lane >> 4) * 128 + (wr + i * 16 + (lane & 15))) * 16;
    bOff[i] = ((lane >> 4) * 128 + (wc + i * 16 + (lane & 15))) * 16;
  }

  const int nt = (int)(K >> 5);

  auto STAGE = [&](int buf, int t) {
    const long koff = (long)t << 5;
#pragma unroll
    for (int j = 0; j < 2; ++j) {
      gload16(aS + koff + j * 16, &ldsA[buf][j * 4096 + ldst]);
      gload16(bS + koff + j * 16, &ldsB[buf][j * 4096 + ldst]);
    }
  };

  STAGE(0, 0);
  __syncthreads();
  int cur = 0;
  for (int t = 0; t < nt; ++t) {
    if (t + 1 < nt) STAGE(cur ^ 1, t + 1);  // prefetch overlaps compute below
    bf16x8 af[4], bfr[4];
#pragma unroll
    for (int i = 0; i < 4; ++i) af[i] = *(const bf16x8*)(&ldsA[cur][aOff[i]]);
#pragma unroll
    for (int i = 0; i < 4; ++i) bfr[i] = *(const bf16x8*)(&ldsB[cur][bOff[i]]);
#pragma unroll
    for (int i = 0; i < 4; ++i)
#pragma unroll
      for (int j = 0; j < 4; ++j)
        acc[i][j] = __builtin_amdgcn_mfma_f32_16x16x32_bf16(af[i], bfr[j], acc[i][j], 0, 0, 0);
    __syncthreads();  // drains prefetch (vmcnt) + guards LDS buffer reuse
    cur ^= 1;
  }

  // epilogue: C/D layout col=lane&15, row=(lane>>4)*4+r  [learn_hip m89]
  const int orow = (lane >> 4) * 4;
  const int ocol = lane & 15;
#pragma unroll
  for (int i = 0; i < 4; ++i) {
    const long gr0 = row0 + wr + i * 16 + orow;
#pragma unroll
    for (int j = 0; j < 4; ++j) {
      const long gc = col0 + wc + j * 16 + ocol;
      const float bb = bias[gc];
#pragma unroll
      for (int r = 0; r < 4; ++r) {
        const long gr = gr0 + r;
        float v = acc[i][j][r] + bb;
        if (EPI == 1) v += xres[gr * ldo + gc];
        out[gr * ldo + gc] = v;
      }
    }
  }
}

// ---------------- blocked linear scan over T ----------------
// phase 1: per-chunk local scan with s=0 start
__global__ void scan_local_kernel(const float* __restrict__ v, float* __restrict__ s_loc,
                                  const float* __restrict__ td) {
  const int m = threadIdx.x;   // 512
  const int c = blockIdx.x;    // chunk
  const int b = blockIdx.y;
  const float decay = sigm(td[m]) * 0.9f + 0.1f;
  const float* vp = v + ((size_t)b * TT + (size_t)c * CHUNK) * MDIM + m;
  float s = 0.f;
#pragma unroll 8
  for (int t = 0; t < CHUNK; ++t) s = s * decay + vp[(size_t)t * MDIM];
  s_loc[((size_t)b * NCH + c) * MDIM + m] = s;
}

// phase 2: scan across chunks (carry factor decay^CHUNK); emits next_memory
__global__ void scan_chunks_kernel(const float* __restrict__ s_loc, const float* __restrict__ mem0,
                                   float* __restrict__ s_in, float* __restrict__ nextmem,
                                   const float* __restrict__ td) {
  const int m = threadIdx.x;
  const int b = blockIdx.x;
  const float decay = sigm(td[m]) * 0.9f + 0.1f;
  const float d2 = decay * decay, d4 = d2 * d2, d8 = d4 * d4;
  const float d16 = d8 * d8, d32 = d16 * d16, dL = d32 * d32;  // decay^64
  float s = mem0[(size_t)b * MDIM + m];
  for (int c = 0; c < NCH; ++c) {
    const size_t idx = ((size_t)b * NCH + c) * MDIM + m;
    s_in[idx] = s;
    s = s * dL + s_loc[idx];
  }
  nextmem[(size_t)b * MDIM + m] = s;
}

// phase 3: replay with correct incoming state; write wv as bf16 into combined[:, 2048:]
__global__ void scan_replay_kernel(const float* __restrict__ v, const float* __restrict__ s_in,
                                   unsigned short* __restrict__ comb,
                                   const float* __restrict__ td, const float* __restrict__ tf) {
  const int m = threadIdx.x;
  const int c = blockIdx.x;
  const int b = blockIdx.y;
  const float decay = sigm(td[m]) * 0.9f + 0.1f;
  const float first = sigm(tf[m]);
  float s = s_in[((size_t)b * NCH + c) * MDIM + m];
  const float* vp = v + ((size_t)b * TT + (size_t)c * CHUNK) * MDIM + m;
  unsigned short* wp = comb + ((size_t)b * TT + (size_t)c * CHUNK) * KCAT + DDIM + m;
#pragma unroll 4
  for (int t = 0; t < CHUNK; ++t) {
    const float vv = vp[(size_t)t * MDIM];
    wp[(size_t)t * KCAT] = f2bf(vv + s * first);
    s = s * decay + vv;
  }
}

extern "C" void kernel_launch(void* const* d_in, const int* in_sizes, int n_in,
                              void* d_out, int out_size, void* d_ws, size_t ws_size,
                              hipStream_t stream) {
  const float* x    = (const float*)d_in[0];
  const float* mem0 = (const float*)d_in[1];
  const float* Wv   = (const float*)d_in[2];
  const float* bv   = (const float*)d_in[3];
  const float* Wg   = (const float*)d_in[4];
  const float* bg   = (const float*)d_in[5];
  const float* td   = (const float*)d_in[6];
  const float* tf   = (const float*)d_in[7];

  float* out = (float*)d_out;
  float* nextmem = out + (size_t)NROWS * DDIM;
  float* vbuf = out;  // v scratch lives in d_out; GEMM2 overwrites it at the end

  // workspace layout (~93 MB total)
  unsigned short* comb = (unsigned short*)d_ws;                 // [16384][2560] bf16
  unsigned short* WvB  = comb + (size_t)NROWS * KCAT;           // [512][2048] bf16
  unsigned short* WgB  = WvB + (size_t)MDIM * DDIM;             // [2048][2560] bf16
  float* s_loc = (float*)(WgB + (size_t)DDIM * KCAT);           // [4][64][512] f32
  float* s_in  = s_loc + (size_t)BB * NCH * MDIM;               // [4][64][512] f32

  cvt_x_kernel<<<(NROWS * DDIM / 4) / 256, 256, 0, stream>>>(x, comb);
  cvt_w_kernel<<<(MDIM * DDIM / 4) / 256, 256, 0, stream>>>(Wv, WvB, (long)MDIM * DDIM / 4);
  cvt_w_kernel<<<(DDIM * KCAT / 4) / 256, 256, 0, stream>>>(Wg, WgB, (long)DDIM * KCAT / 4);

  // GEMM1: v = x_bf16 (lda=KCAT, first 2048 cols) @ Wv^T + bv -> vbuf f32 [16384,512]
  gemm_bf16_kernel<0><<<(NROWS / 128) * (MDIM / 128), 256, 0, stream>>>(
      comb, KCAT, WvB, DDIM, vbuf, MDIM, bv, nullptr, NROWS / 128);

  scan_local_kernel<<<dim3(NCH, BB), MDIM, 0, stream>>>(vbuf, s_loc, td);
  scan_chunks_kernel<<<BB, MDIM, 0, stream>>>(s_loc, mem0, s_in, nextmem, td);
  scan_replay_kernel<<<dim3(NCH, BB), MDIM, 0, stream>>>(vbuf, s_in, comb, td, tf);

  // GEMM2: out = x + combined @ Wg^T + bg -> d_out f32 [16384,2048]
  gemm_bf16_kernel<1><<<(NROWS / 128) * (DDIM / 128), 256, 0, stream>>>(
      comb, KCAT, WgB, KCAT, out, DDIM, bg, x, NROWS / 128);
}

// Round 2
// 758.016 us; speedup vs baseline: 1.0774x; 1.0774x over previous
//
#include <hip/hip_runtime.h>
#include <hip/hip_bf16.h>
#include <stdint.h>

// Problem constants (B,T,D,M) = (4,4096,2048,512)
#define BB 4
#define TT 4096
#define DDIM 2048
#define MDIM 512
#define NROWS (BB * TT)          // 16384
#define KCAT (DDIM + MDIM)       // 2560
#define CHUNK 64
#define NCH (TT / CHUNK)         // 64

typedef __attribute__((ext_vector_type(8))) short bf16x8;
typedef __attribute__((ext_vector_type(4))) float f32x4;

#define WAITVM(N) asm volatile("s_waitcnt vmcnt(" #N ")" ::: "memory")
#define SBAR()    asm volatile("s_barrier" ::: "memory")

__device__ __forceinline__ unsigned short f2bf(float f) {
  unsigned u = __float_as_uint(f);
  return (unsigned short)((u + 0x7fffu + ((u >> 16) & 1u)) >> 16);  // RNE
}
__device__ __forceinline__ float sigm(float x) { return 1.0f / (1.0f + expf(-x)); }

__device__ __forceinline__ void gload16(const void* g, void* l) {
  __builtin_amdgcn_global_load_lds(
      (const __attribute__((address_space(1))) unsigned int*)g,
      (__attribute__((address_space(3))) unsigned int*)l, 16, 0, 0);
}

// ---------------- conversions ----------------
__global__ void cvt_x_kernel(const float* __restrict__ x, unsigned short* __restrict__ comb) {
  size_t i = (size_t)blockIdx.x * 256 + threadIdx.x;  // one float4 per thread
  size_t row = i >> 9;           // 512 float4 per row
  size_t c = (i & 511) << 2;
  float4 f = ((const float4*)x)[i];
  ushort4 o;
  o.x = f2bf(f.x); o.y = f2bf(f.y); o.z = f2bf(f.z); o.w = f2bf(f.w);
  *((ushort4*)(comb + row * KCAT + c)) = o;
}

__global__ void cvt_w_kernel(const float* __restrict__ src, unsigned short* __restrict__ dst, long n4) {
  long i = (long)blockIdx.x * 256 + threadIdx.x;
  if (i >= n4) return;
  float4 f = ((const float4*)src)[i];
  ushort4 o;
  o.x = f2bf(f.x); o.y = f2bf(f.y); o.z = f2bf(f.z); o.w = f2bf(f.w);
  ((ushort4*)dst)[i] = o;
}

// ---------------- GEMM: out[r,c] = sum_k A[r,k]*B[c,k] (+bias, +x residual) ----------------
// 128x128 tile, BK=32, 4 waves (2x2 of 64x64), 16x16x32 bf16 MFMA.
// 3 LDS buffers, depth-2 prefetch, counted vmcnt (never 0 in steady state),
// raw s_barrier (no vmcnt drain). LDS k-block-major [BK/8][128][8] -> staging
// is linear (global_load_lds) and ds_read_b128 is conflict-free (measured 0).
template<int EPI>
__global__ __launch_bounds__(256, 3) void gemm_bf16_kernel(
    const unsigned short* __restrict__ A, long lda,  // [rows, K] row-major, stride lda
    const unsigned short* __restrict__ B, long K,    // [N, K] row-major (B^T form)
    float* __restrict__ out, long ldo,
    const float* __restrict__ bias,                  // [N]
    const float* __restrict__ xres,                  // EPI==1: residual [rows, ldo]
    int ncb)                                         // number of col blocks
{
  __shared__ __align__(16) unsigned char ldsA[3][8192];
  __shared__ __align__(16) unsigned char ldsB[3][8192];

  const int tid = threadIdx.x;
  const int nwg = gridDim.x;
  int lin = blockIdx.x;
  // bijective XCD swizzle (all our grids are multiples of 8)
  lin = (lin & 7) * (nwg >> 3) + (lin >> 3);
  // row-panel-major: resident blocks share the (large) A row panel; B stays L2-hot
  const long row0 = (long)(lin / ncb) * 128;
  const long col0 = (long)(lin % ncb) * 128;

  const int lane = tid & 63;
  const int wave = tid >> 6;
  const int wr = (wave >> 1) * 64;
  const int wc = (wave & 1) * 64;

  // staging: per issue j, LDS linear byte off = j*4096 + tid*16
  //   -> kblock = j*2 + (tid>>7), row = tid&127
  const int srow = tid & 127;
  const unsigned short* aS = A + (row0 + srow) * lda + (tid >> 7) * 8;
  const unsigned short* bS = B + (col0 + srow) * K + (tid >> 7) * 8;
  const int ldst = tid * 16;

  f32x4 acc[4][4];
#pragma unroll
  for (int i = 0; i < 4; ++i)
#pragma unroll
    for (int j = 0; j < 4; ++j)
      acc[i][j] = {0.f, 0.f, 0.f, 0.f};

  // fragment LDS byte offsets: [kblock=lane>>4][row][8elem]
  int aOff[4], bOff[4];
#pragma unroll
  for (int i = 0; i < 4; ++i) {
    aOff[i] = ((lane >> 4) * 128 + (wr + i * 16 + (lane & 15))) * 16;
    bOff[i] = ((lane >> 4) * 128 + (wc + i * 16 + (lane & 15))) * 16;
  }

  const int nt = (int)(K >> 5);

  auto STAGE = [&](int buf, int t) {
    const long koff = (long)t << 5;
#pragma unroll
    for (int j = 0; j < 2; ++j) {
      gload16(aS + koff + j * 16, &ldsA[buf][j * 4096 + ldst]);
      gload16(bS + koff + j * 16, &ldsB[buf][j * 4096 + ldst]);
    }
  };

  auto COMPUTE = [&](int cb) {
    bf16x8 af[4], bfr[4];
#pragma unroll
    for (int i = 0; i < 4; ++i) af[i] = *(const bf16x8*)(&ldsA[cb][aOff[i]]);
#pragma unroll
    for (int i = 0; i < 4; ++i) bfr[i] = *(const bf16x8*)(&ldsB[cb][bOff[i]]);
    __builtin_amdgcn_s_setprio(1);
#pragma unroll
    for (int i = 0; i < 4; ++i)
#pragma unroll
      for (int j = 0; j < 4; ++j)
        acc[i][j] = __builtin_amdgcn_mfma_f32_16x16x32_bf16(af[i], bfr[j], acc[i][j], 0, 0, 0);
    __builtin_amdgcn_s_setprio(0);
  };

  // depth-2 pipeline: buffers cycle 0,1,2; tile t lives in buffer t%3.
  STAGE(0, 0);
  STAGE(1, 1);
  int cur = 0, stg = 2;
  for (int t = 0; t < nt - 2; ++t) {
    WAITVM(4);            // my 4 issues for tile t landed (t+1's 4 still in flight)
    SBAR();               // all waves' tile-t writes visible; all done reading buf stg
    STAGE(stg, t + 2);    // issue early; latency hides under MFMA of t, t+1
    COMPUTE(cur);
    cur = (cur == 2) ? 0 : cur + 1;
    stg = (stg == 2) ? 0 : stg + 1;
  }
  // t = nt-2: tile nt-1 still in flight
  WAITVM(4);
  SBAR();
  COMPUTE(cur);
  cur = (cur == 2) ? 0 : cur + 1;
  // t = nt-1: last tile, drain
  WAITVM(0);
  SBAR();
  COMPUTE(cur);

  // epilogue: C/D layout col=lane&15, row=(lane>>4)*4+r  [learn_hip m89]
  const int orow = (lane >> 4) * 4;
  const int ocol = lane & 15;
#pragma unroll
  for (int i = 0; i < 4; ++i) {
    const long gr0 = row0 + wr + i * 16 + orow;
#pragma unroll
    for (int j = 0; j < 4; ++j) {
      const long gc = col0 + wc + j * 16 + ocol;
      const float bb = bias[gc];
#pragma unroll
      for (int r = 0; r < 4; ++r) {
        const long gr = gr0 + r;
        float v = acc[i][j][r] + bb;
        if (EPI == 1) v += xres[gr * ldo + gc];
        out[gr * ldo + gc] = v;
      }
    }
  }
}

// ---------------- blocked linear scan over T ----------------
__global__ void scan_local_kernel(const float* __restrict__ v, float* __restrict__ s_loc,
                                  const float* __restrict__ td) {
  const int m = threadIdx.x;   // 512
  const int c = blockIdx.x;    // chunk
  const int b = blockIdx.y;
  const float decay = sigm(td[m]) * 0.9f + 0.1f;
  const float* vp = v + ((size_t)b * TT + (size_t)c * CHUNK) * MDIM + m;
  float s = 0.f;
#pragma unroll 8
  for (int t = 0; t < CHUNK; ++t) s = s * decay + vp[(size_t)t * MDIM];
  s_loc[((size_t)b * NCH + c) * MDIM + m] = s;
}

__global__ void scan_chunks_kernel(const float* __restrict__ s_loc, const float* __restrict__ mem0,
                                   float* __restrict__ s_in, float* __restrict__ nextmem,
                                   const float* __restrict__ td) {
  const int m = threadIdx.x;
  const int b = blockIdx.x;
  const float decay = sigm(td[m]) * 0.9f + 0.1f;
  const float d2 = decay * decay, d4 = d2 * d2, d8 = d4 * d4;
  const float d16 = d8 * d8, d32 = d16 * d16, dL = d32 * d32;  // decay^64
  float s = mem0[(size_t)b * MDIM + m];
  for (int c = 0; c < NCH; ++c) {
    const size_t idx = ((size_t)b * NCH + c) * MDIM + m;
    s_in[idx] = s;
    s = s * dL + s_loc[idx];
  }
  nextmem[(size_t)b * MDIM + m] = s;
}

__global__ void scan_replay_kernel(const float* __restrict__ v, const float* __restrict__ s_in,
                                   unsigned short* __restrict__ comb,
                                   const float* __restrict__ td, const float* __restrict__ tf) {
  const int m = threadIdx.x;
  const int c = blockIdx.x;
  const int b = blockIdx.y;
  const float decay = sigm(td[m]) * 0.9f + 0.1f;
  const float first = sigm(tf[m]);
  float s = s_in[((size_t)b * NCH + c) * MDIM + m];
  const float* vp = v + ((size_t)b * TT + (size_t)c * CHUNK) * MDIM + m;
  unsigned short* wp = comb + ((size_t)b * TT + (size_t)c * CHUNK) * KCAT + DDIM + m;
#pragma unroll 4
  for (int t = 0; t < CHUNK; ++t) {
    const float vv = vp[(size_t)t * MDIM];
    wp[(size_t)t * KCAT] = f2bf(vv + s * first);
    s = s * decay + vv;
  }
}

extern "C" void kernel_launch(void* const* d_in, const int* in_sizes, int n_in,
                              void* d_out, int out_size, void* d_ws, size_t ws_size,
                              hipStream_t stream) {
  const float* x    = (const float*)d_in[0];
  const float* mem0 = (const float*)d_in[1];
  const float* Wv   = (const float*)d_in[2];
  const float* bv   = (const float*)d_in[3];
  const float* Wg   = (const float*)d_in[4];
  const float* bg   = (const float*)d_in[5];
  const float* td   = (const float*)d_in[6];
  const float* tf   = (const float*)d_in[7];

  float* out = (float*)d_out;
  float* nextmem = out + (size_t)NROWS * DDIM;
  float* vbuf = out;  // v scratch lives in d_out; GEMM2 overwrites it at the end

  // workspace layout (~93 MB total)
  unsigned short* comb = (unsigned short*)d_ws;                 // [16384][2560] bf16
  unsigned short* WvB  = comb + (size_t)NROWS * KCAT;           // [512][2048] bf16
  unsigned short* WgB  = WvB + (size_t)MDIM * DDIM;             // [2048][2560] bf16
  float* s_loc = (float*)(WgB + (size_t)DDIM * KCAT);           // [4][64][512] f32
  float* s_in  = s_loc + (size_t)BB * NCH * MDIM;               // [4][64][512] f32

  cvt_x_kernel<<<(NROWS * DDIM / 4) / 256, 256, 0, stream>>>(x, comb);
  cvt_w_kernel<<<(MDIM * DDIM / 4) / 256, 256, 0, stream>>>(Wv, WvB, (long)MDIM * DDIM / 4);
  cvt_w_kernel<<<(DDIM * KCAT / 4) / 256, 256, 0, stream>>>(Wg, WgB, (long)DDIM * KCAT / 4);

  // GEMM1: v = x_bf16 (lda=KCAT, first 2048 cols) @ Wv^T + bv -> vbuf f32 [16384,512]
  gemm_bf16_kernel<0><<<(NROWS / 128) * (MDIM / 128), 256, 0, stream>>>(
      comb, KCAT, WvB, DDIM, vbuf, MDIM, bv, nullptr, MDIM / 128);

  scan_local_kernel<<<dim3(NCH, BB), MDIM, 0, stream>>>(vbuf, s_loc, td);
  scan_chunks_kernel<<<BB, MDIM, 0, stream>>>(s_loc, mem0, s_in, nextmem, td);
  scan_replay_kernel<<<dim3(NCH, BB), MDIM, 0, stream>>>(vbuf, s_in, comb, td, tf);

  // GEMM2: out = x + combined @ Wg^T + bg -> d_out f32 [16384,2048]
  gemm_bf16_kernel<1><<<(NROWS / 128) * (DDIM / 128), 256, 0, stream>>>(
      comb, KCAT, WgB, KCAT, out, DDIM, bg, x, DDIM / 128);
}

// Round 3
// 552.209 us; speedup vs baseline: 1.4790x; 1.3727x over previous
//
#include <hip/hip_runtime.h>
#include <hip/hip_bf16.h>
#include <stdint.h>

// Problem constants (B,T,D,M) = (4,4096,2048,512)
#define BB 4
#define TT 4096
#define DDIM 2048
#define MDIM 512
#define NROWS (BB * TT)          // 16384
#define KCAT (DDIM + MDIM)       // 2560
#define CHUNK 64
#define NCH (TT / CHUNK)         // 64

typedef __attribute__((ext_vector_type(8))) short bf16x8;
typedef __attribute__((ext_vector_type(4))) float f32x4;

#define WAITVM(N) asm volatile("s_waitcnt vmcnt(" #N ")" ::: "memory")
#define SBAR()    asm volatile("s_barrier" ::: "memory")

__device__ __forceinline__ unsigned short f2bf(float f) {
  unsigned u = __float_as_uint(f);
  return (unsigned short)((u + 0x7fffu + ((u >> 16) & 1u)) >> 16);  // RNE
}
__device__ __forceinline__ float sigm(float x) { return 1.0f / (1.0f + expf(-x)); }

__device__ __forceinline__ void gload16(const void* g, void* l) {
  __builtin_amdgcn_global_load_lds(
      (const __attribute__((address_space(1))) unsigned int*)g,
      (__attribute__((address_space(3))) unsigned int*)l, 16, 0, 0);
}

// ---------------- conversions ----------------
__global__ void cvt_x_kernel(const float* __restrict__ x, unsigned short* __restrict__ comb) {
  size_t i = (size_t)blockIdx.x * 256 + threadIdx.x;  // one float4 per thread
  size_t row = i >> 9;           // 512 float4 per row
  size_t c = (i & 511) << 2;
  float4 f = ((const float4*)x)[i];
  ushort4 o;
  o.x = f2bf(f.x); o.y = f2bf(f.y); o.z = f2bf(f.z); o.w = f2bf(f.w);
  *((ushort4*)(comb + row * KCAT + c)) = o;
}

__global__ void cvt_w_kernel(const float* __restrict__ src, unsigned short* __restrict__ dst, long n4) {
  long i = (long)blockIdx.x * 256 + threadIdx.x;
  if (i >= n4) return;
  float4 f = ((const float4*)src)[i];
  ushort4 o;
  o.x = f2bf(f.x); o.y = f2bf(f.y); o.z = f2bf(f.z); o.w = f2bf(f.w);
  ((ushort4*)dst)[i] = o;
}

// ---------------- GEMM: out[r,c] = sum_k A[r,k]*B[c,k] (+bias, +x residual) ----------------
// 128x128 tile, BK=32, 4 waves (2x2 of 64x64), 16x16x32 bf16 MFMA.
// LDS tile: row-major [128 rows][4 kq][16B] with XOR slot swizzle
//   slot(row,kq) = kq ^ ((row>>1)&3)
// Staging is lane-linear (global_load_lds) with the INVERSE permutation applied
// to the global source column (rule #21: swizzle source + read, dest linear).
// Coalescing: each staging instruction = 16 rows x 64 contiguous bytes
// (16 segments, 4x fewer transactions than one-row-per-lane).
// ds_read_b128: 8 lanes per 16B bank-quad per wave -> conflict-free.
template<int EPI>
__global__ __launch_bounds__(256, 3) void gemm_bf16_kernel(
    const unsigned short* __restrict__ A, long lda,  // [rows, K] row-major, stride lda
    const unsigned short* __restrict__ B, long K,    // [N, K] row-major (B^T form)
    float* __restrict__ out, long ldo,
    const float* __restrict__ bias,                  // [N]
    const float* __restrict__ xres,                  // EPI==1: residual [rows, ldo]
    int ncb)                                         // number of col blocks
{
  __shared__ __align__(16) unsigned char ldsA[3][8192];
  __shared__ __align__(16) unsigned char ldsB[3][8192];

  const int tid = threadIdx.x;
  const int nwg = gridDim.x;
  int lin = blockIdx.x;
  // bijective XCD swizzle (all our grids are multiples of 8)
  lin = (lin & 7) * (nwg >> 3) + (lin >> 3);
  // row-panel-major: resident blocks share the (large) A row panel; B stays L2-hot
  const long row0 = (long)(lin / ncb) * 128;
  const long col0 = (long)(lin % ncb) * 128;

  const int lane = tid & 63;
  const int wave = tid >> 6;
  const int wr = (wave >> 1) * 64;
  const int wc = (wave & 1) * 64;

  // staging: thread t writes LDS linear bytes (j*4096 + t*16) of the tile.
  // Linear cell (row = j*64 + t/4, slot = t&3) holds kq = slot ^ ((row>>1)&3)
  //   = (t&3) ^ ((t>>3)&3)   (j*64 contributes 0 mod 4 to row>>1).
  const int srow = tid >> 2;                               // 0..63 (+ j*64)
  const int skq = ((tid & 3) ^ ((tid >> 3) & 3)) * 8;      // element offset in BK
  const unsigned short* aS = A + (row0 + srow) * lda + skq;
  const unsigned short* bS = B + (col0 + srow) * K + skq;
  const int ldst = tid * 16;

  f32x4 acc[4][4];
#pragma unroll
  for (int i = 0; i < 4; ++i)
#pragma unroll
    for (int j = 0; j < 4; ++j)
      acc[i][j] = {0.f, 0.f, 0.f, 0.f};

  // fragment LDS byte offsets: row*64 + slot*16, slot = laneK ^ ((row>>1)&3)
  int aOff[4], bOff[4];
#pragma unroll
  for (int i = 0; i < 4; ++i) {
    const int ra = wr + i * 16 + (lane & 15);
    const int rb = wc + i * 16 + (lane & 15);
    aOff[i] = ra * 64 + ((((lane >> 4) ^ ((ra >> 1) & 3))) << 4);
    bOff[i] = rb * 64 + ((((lane >> 4) ^ ((rb >> 1) & 3))) << 4);
  }

  const int nt = (int)(K >> 5);

  auto STAGE = [&](int buf, int t) {
    const long koff = (long)t << 5;  // elements
#pragma unroll
    for (int j = 0; j < 2; ++j) {
      gload16(aS + koff + (long)j * 64 * lda, &ldsA[buf][j * 4096 + ldst]);
      gload16(bS + koff + (long)j * 64 * K, &ldsB[buf][j * 4096 + ldst]);
    }
  };

  auto COMPUTE = [&](int cb) {
    bf16x8 af[4], bfr[4];
#pragma unroll
    for (int i = 0; i < 4; ++i) af[i] = *(const bf16x8*)(&ldsA[cb][aOff[i]]);
#pragma unroll
    for (int i = 0; i < 4; ++i) bfr[i] = *(const bf16x8*)(&ldsB[cb][bOff[i]]);
    __builtin_amdgcn_s_setprio(1);
#pragma unroll
    for (int i = 0; i < 4; ++i)
#pragma unroll
      for (int j = 0; j < 4; ++j)
        acc[i][j] = __builtin_amdgcn_mfma_f32_16x16x32_bf16(af[i], bfr[j], acc[i][j], 0, 0, 0);
    __builtin_amdgcn_s_setprio(0);
  };

  // depth-2 pipeline: buffers cycle 0,1,2; tile t lives in buffer t%3.
  STAGE(0, 0);
  STAGE(1, 1);
  int cur = 0, stg = 2;
  for (int t = 0; t < nt - 2; ++t) {
    WAITVM(4);            // my 4 issues for tile t landed (t+1's 4 still in flight)
    SBAR();               // all waves' tile-t writes visible; all done reading buf stg
    STAGE(stg, t + 2);    // issue early; latency hides under MFMA of t, t+1
    COMPUTE(cur);
    cur = (cur == 2) ? 0 : cur + 1;
    stg = (stg == 2) ? 0 : stg + 1;
  }
  // t = nt-2: tile nt-1 still in flight
  WAITVM(4);
  SBAR();
  COMPUTE(cur);
  cur = (cur == 2) ? 0 : cur + 1;
  // t = nt-1: last tile, drain
  WAITVM(0);
  SBAR();
  COMPUTE(cur);

  // epilogue: C/D layout col=lane&15, row=(lane>>4)*4+r  [learn_hip m89]
  const int orow = (lane >> 4) * 4;
  const int ocol = lane & 15;
#pragma unroll
  for (int i = 0; i < 4; ++i) {
    const long gr0 = row0 + wr + i * 16 + orow;
#pragma unroll
    for (int j = 0; j < 4; ++j) {
      const long gc = col0 + wc + j * 16 + ocol;
      const float bb = bias[gc];
#pragma unroll
      for (int r = 0; r < 4; ++r) {
        const long gr = gr0 + r;
        float v = acc[i][j][r] + bb;
        if (EPI == 1) v += xres[gr * ldo + gc];
        out[gr * ldo + gc] = v;
      }
    }
  }
}

// ---------------- blocked linear scan over T ----------------
__global__ void scan_local_kernel(const float* __restrict__ v, float* __restrict__ s_loc,
                                  const float* __restrict__ td) {
  const int m = threadIdx.x;   // 512
  const int c = blockIdx.x;    // chunk
  const int b = blockIdx.y;
  const float decay = sigm(td[m]) * 0.9f + 0.1f;
  const float* vp = v + ((size_t)b * TT + (size_t)c * CHUNK) * MDIM + m;
  float s = 0.f;
#pragma unroll 8
  for (int t = 0; t < CHUNK; ++t) s = s * decay + vp[(size_t)t * MDIM];
  s_loc[((size_t)b * NCH + c) * MDIM + m] = s;
}

__global__ void scan_chunks_kernel(const float* __restrict__ s_loc, const float* __restrict__ mem0,
                                   float* __restrict__ s_in, float* __restrict__ nextmem,
                                   const float* __restrict__ td) {
  const int m = threadIdx.x;
  const int b = blockIdx.x;
  const float decay = sigm(td[m]) * 0.9f + 0.1f;
  const float d2 = decay * decay, d4 = d2 * d2, d8 = d4 * d4;
  const float d16 = d8 * d8, d32 = d16 * d16, dL = d32 * d32;  // decay^64
  float s = mem0[(size_t)b * MDIM + m];
  for (int c = 0; c < NCH; ++c) {
    const size_t idx = ((size_t)b * NCH + c) * MDIM + m;
    s_in[idx] = s;
    s = s * dL + s_loc[idx];
  }
  nextmem[(size_t)b * MDIM + m] = s;
}

__global__ void scan_replay_kernel(const float* __restrict__ v, const float* __restrict__ s_in,
                                   unsigned short* __restrict__ comb,
                                   const float* __restrict__ td, const float* __restrict__ tf) {
  const int m = threadIdx.x;
  const int c = blockIdx.x;
  const int b = blockIdx.y;
  const float decay = sigm(td[m]) * 0.9f + 0.1f;
  const float first = sigm(tf[m]);
  float s = s_in[((size_t)b * NCH + c) * MDIM + m];
  const float* vp = v + ((size_t)b * TT + (size_t)c * CHUNK) * MDIM + m;
  unsigned short* wp = comb + ((size_t)b * TT + (size_t)c * CHUNK) * KCAT + DDIM + m;
#pragma unroll 4
  for (int t = 0; t < CHUNK; ++t) {
    const float vv = vp[(size_t)t * MDIM];
    wp[(size_t)t * KCAT] = f2bf(vv + s * first);
    s = s * decay + vv;
  }
}

extern "C" void kernel_launch(void* const* d_in, const int* in_sizes, int n_in,
                              void* d_out, int out_size, void* d_ws, size_t ws_size,
                              hipStream_t stream) {
  const float* x    = (const float*)d_in[0];
  const float* mem0 = (const float*)d_in[1];
  const float* Wv   = (const float*)d_in[2];
  const float* bv   = (const float*)d_in[3];
  const float* Wg   = (const float*)d_in[4];
  const float* bg   = (const float*)d_in[5];
  const float* td   = (const float*)d_in[6];
  const float* tf   = (const float*)d_in[7];

  float* out = (float*)d_out;
  float* nextmem = out + (size_t)NROWS * DDIM;
  float* vbuf = out;  // v scratch lives in d_out; GEMM2 overwrites it at the end

  // workspace layout (~93 MB total)
  unsigned short* comb = (unsigned short*)d_ws;                 // [16384][2560] bf16
  unsigned short* WvB  = comb + (size_t)NROWS * KCAT;           // [512][2048] bf16
  unsigned short* WgB  = WvB + (size_t)MDIM * DDIM;             // [2048][2560] bf16
  float* s_loc = (float*)(WgB + (size_t)DDIM * KCAT);           // [4][64][512] f32
  float* s_in  = s_loc + (size_t)BB * NCH * MDIM;               // [4][64][512] f32

  cvt_x_kernel<<<(NROWS * DDIM / 4) / 256, 256, 0, stream>>>(x, comb);
  cvt_w_kernel<<<(MDIM * DDIM / 4) / 256, 256, 0, stream>>>(Wv, WvB, (long)MDIM * DDIM / 4);
  cvt_w_kernel<<<(DDIM * KCAT / 4) / 256, 256, 0, stream>>>(Wg, WgB, (long)DDIM * KCAT / 4);

  // GEMM1: v = x_bf16 (lda=KCAT, first 2048 cols) @ Wv^T + bv -> vbuf f32 [16384,512]
  gemm_bf16_kernel<0><<<(NROWS / 128) * (MDIM / 128), 256, 0, stream>>>(
      comb, KCAT, WvB, DDIM, vbuf, MDIM, bv, nullptr, MDIM / 128);

  scan_local_kernel<<<dim3(NCH, BB), MDIM, 0, stream>>>(vbuf, s_loc, td);
  scan_chunks_kernel<<<BB, MDIM, 0, stream>>>(s_loc, mem0, s_in, nextmem, td);
  scan_replay_kernel<<<dim3(NCH, BB), MDIM, 0, stream>>>(vbuf, s_in, comb, td, tf);

  // GEMM2: out = x + combined @ Wg^T + bg -> d_out f32 [16384,2048]
  gemm_bf16_kernel<1><<<(NROWS / 128) * (DDIM / 128), 256, 0, stream>>>(
      comb, KCAT, WgB, KCAT, out, DDIM, bg, x, DDIM / 128);
}

// Round 5
// 490.994 us; speedup vs baseline: 1.6633x; 1.1247x over previous
//
#include <hip/hip_runtime.h>
#include <hip/hip_bf16.h>
#include <stdint.h>

// Problem constants (B,T,D,M) = (4,4096,2048,512)
#define BB 4
#define TT 4096
#define DDIM 2048
#define MDIM 512
#define NROWS (BB * TT)          // 16384
#define KCAT (DDIM + MDIM)       // 2560
#define CHUNK 64
#define NCH (TT / CHUNK)         // 64

typedef __attribute__((ext_vector_type(8))) short bf16x8;
typedef __attribute__((ext_vector_type(4))) float f32x4;

#define WAITVM(N) asm volatile("s_waitcnt vmcnt(" #N ")" ::: "memory")
#define SBAR()    asm volatile("s_barrier" ::: "memory")

__device__ __forceinline__ unsigned short f2bf(float f) {
  unsigned u = __float_as_uint(f);
  return (unsigned short)((u + 0x7fffu + ((u >> 16) & 1u)) >> 16);  // RNE
}
__device__ __forceinline__ float sigm(float x) { return 1.0f / (1.0f + expf(-x)); }

__device__ __forceinline__ void gload16(const void* g, void* l) {
  __builtin_amdgcn_global_load_lds(
      (const __attribute__((address_space(1))) unsigned int*)g,
      (__attribute__((address_space(3))) unsigned int*)l, 16, 0, 0);
}

// ---------------- conversions ----------------
__global__ void cvt_x_kernel(const float* __restrict__ x, unsigned short* __restrict__ comb) {
  size_t i = (size_t)blockIdx.x * 256 + threadIdx.x;  // one float4 per thread
  size_t row = i >> 9;           // 512 float4 per row
  size_t c = (i & 511) << 2;
  float4 f = ((const float4*)x)[i];
  ushort4 o;
  o.x = f2bf(f.x); o.y = f2bf(f.y); o.z = f2bf(f.z); o.w = f2bf(f.w);
  *((ushort4*)(comb + row * KCAT + c)) = o;
}

__global__ void cvt_w_kernel(const float* __restrict__ src, unsigned short* __restrict__ dst, long n4) {
  long i = (long)blockIdx.x * 256 + threadIdx.x;
  if (i >= n4) return;
  float4 f = ((const float4*)src)[i];
  ushort4 o;
  o.x = f2bf(f.x); o.y = f2bf(f.y); o.z = f2bf(f.z); o.w = f2bf(f.w);
  ((ushort4*)dst)[i] = o;
}

// ---------------- 128x128 GEMM (kept for GEMM1: N=512 needs many blocks) ----------------
template<int EPI>
__global__ __launch_bounds__(256, 3) void gemm_bf16_kernel(
    const unsigned short* __restrict__ A, long lda,
    const unsigned short* __restrict__ B, long K,
    float* __restrict__ out, long ldo,
    const float* __restrict__ bias,
    const float* __restrict__ xres,
    int ncb)
{
  __shared__ __align__(16) unsigned char ldsA[3][8192];
  __shared__ __align__(16) unsigned char ldsB[3][8192];

  const int tid = threadIdx.x;
  const int nwg = gridDim.x;
  int lin = blockIdx.x;
  lin = (lin & 7) * (nwg >> 3) + (lin >> 3);
  const long row0 = (long)(lin / ncb) * 128;
  const long col0 = (long)(lin % ncb) * 128;

  const int lane = tid & 63;
  const int wave = tid >> 6;
  const int wr = (wave >> 1) * 64;
  const int wc = (wave & 1) * 64;

  const int srow = tid >> 2;                               // 0..63 (+ j*64)
  const int skq = ((tid & 3) ^ ((tid >> 3) & 3)) * 8;
  const unsigned short* aS = A + (row0 + srow) * lda + skq;
  const unsigned short* bS = B + (col0 + srow) * K + skq;
  const int ldst = tid * 16;

  f32x4 acc[4][4];
#pragma unroll
  for (int i = 0; i < 4; ++i)
#pragma unroll
    for (int j = 0; j < 4; ++j)
      acc[i][j] = {0.f, 0.f, 0.f, 0.f};

  int aOff[4], bOff[4];
#pragma unroll
  for (int i = 0; i < 4; ++i) {
    const int ra = wr + i * 16 + (lane & 15);
    const int rb = wc + i * 16 + (lane & 15);
    aOff[i] = ra * 64 + ((((lane >> 4) ^ ((ra >> 1) & 3))) << 4);
    bOff[i] = rb * 64 + ((((lane >> 4) ^ ((rb >> 1) & 3))) << 4);
  }

  const int nt = (int)(K >> 5);

  auto STAGE = [&](int buf, int t) {
    const long koff = (long)t << 5;
#pragma unroll
    for (int j = 0; j < 2; ++j) {
      gload16(aS + koff + (long)j * 64 * lda, &ldsA[buf][j * 4096 + ldst]);
      gload16(bS + koff + (long)j * 64 * K, &ldsB[buf][j * 4096 + ldst]);
    }
  };

  auto COMPUTE = [&](int cb) {
    bf16x8 af[4], bfr[4];
#pragma unroll
    for (int i = 0; i < 4; ++i) af[i] = *(const bf16x8*)(&ldsA[cb][aOff[i]]);
#pragma unroll
    for (int i = 0; i < 4; ++i) bfr[i] = *(const bf16x8*)(&ldsB[cb][bOff[i]]);
    __builtin_amdgcn_s_setprio(1);
#pragma unroll
    for (int i = 0; i < 4; ++i)
#pragma unroll
      for (int j = 0; j < 4; ++j)
        acc[i][j] = __builtin_amdgcn_mfma_f32_16x16x32_bf16(af[i], bfr[j], acc[i][j], 0, 0, 0);
    __builtin_amdgcn_s_setprio(0);
  };

  STAGE(0, 0);
  STAGE(1, 1);
  int cur = 0, stg = 2;
  for (int t = 0; t < nt - 2; ++t) {
    WAITVM(4);
    SBAR();
    STAGE(stg, t + 2);
    COMPUTE(cur);
    cur = (cur == 2) ? 0 : cur + 1;
    stg = (stg == 2) ? 0 : stg + 1;
  }
  WAITVM(4);
  SBAR();
  COMPUTE(cur);
  cur = (cur == 2) ? 0 : cur + 1;
  WAITVM(0);
  SBAR();
  COMPUTE(cur);

  const int orow = (lane >> 4) * 4;
  const int ocol = lane & 15;
#pragma unroll
  for (int i = 0; i < 4; ++i) {
    const long gr0 = row0 + wr + i * 16 + orow;
#pragma unroll
    for (int j = 0; j < 4; ++j) {
      const long gc = col0 + wc + j * 16 + ocol;
      const float bb = bias[gc];
#pragma unroll
      for (int r = 0; r < 4; ++r) {
        const long gr = gr0 + r;
        float v = acc[i][j][r] + bb;
        if (EPI == 1) v += xres[gr * ldo + gc];
        out[gr * ldo + gc] = v;
      }
    }
  }
}

// ---------------- 256x256 GEMM, 8 waves, 2-phase-per-K-tile schedule (GEMM2) ----------------
// BK=32, 3 LDS buffers (96 KB), depth-2 counted-vmcnt pipeline (R3-verified
// skeleton), per K-tile two phases of {ds_read subtile + 2 gload -> barrier ->
// setprio/16 MFMA -> barrier}. Per-wave output 128x64 (8x4 frags) -> 64 MFMA
// per 24 ds_read_b128 per K-tile: LDS off the critical path.
// LDS tile: [256 rows][4 slots][16B], slot = kq ^ (row&3); staging linear
// (global_load_lds) with inverse permutation on global source column.
// RESID: epilogue adds bf16 residual read from A (= comb, cols 0..2047).
template<int RESID>
__global__ __launch_bounds__(512, 2) void gemm256_kernel(
    const unsigned short* __restrict__ A, long lda,
    const unsigned short* __restrict__ B, long K,
    float* __restrict__ out, long ldo,
    const float* __restrict__ bias,
    int ncb)
{
  __shared__ __align__(16) unsigned char ldsA[3][16384];
  __shared__ __align__(16) unsigned char ldsB[3][16384];

  const int tid = threadIdx.x;
  const int nwg = gridDim.x;
  int lin = blockIdx.x;
  lin = (lin & 7) * (nwg >> 3) + (lin >> 3);       // bijective XCD swizzle
  const long row0 = (long)(lin / ncb) * 256;
  const long col0 = (long)(lin % ncb) * 256;

  const int lane = tid & 63;
  const int wave = tid >> 6;            // 0..7
  const int wr = (wave >> 2) * 128;     // wave rows: 0 / 128
  const int wc = (wave & 3) * 64;       // wave cols: 0,64,128,192

  // staging: thread t, issue j writes LDS bytes j*8192 + t*16
  //   -> row = j*128 + t/4, slot = t&3, content kq = slot ^ (row&3)
  const int srow = tid >> 2;                               // 0..127
  const int skq = ((tid & 3) ^ ((tid >> 2) & 3)) * 8;      // element offset
  const unsigned short* aS = A + (row0 + srow) * lda + skq;
  const unsigned short* bS = B + (col0 + srow) * K + skq;
  const int ldst = tid * 16;

  f32x4 acc[8][4];
#pragma unroll
  for (int i = 0; i < 8; ++i)
#pragma unroll
    for (int j = 0; j < 4; ++j)
      acc[i][j] = {0.f, 0.f, 0.f, 0.f};

  // read offsets: byte = row*64 + (kq ^ (row&3))*16; row&3 == lane&3 for all frags
  const int slotb = ((lane >> 4) ^ (lane & 3)) << 4;
  int aOff[8], bOff[4];
#pragma unroll
  for (int h = 0; h < 2; ++h)
#pragma unroll
    for (int ii = 0; ii < 4; ++ii)
      aOff[h * 4 + ii] = (wr + h * 64 + ii * 16 + (lane & 15)) * 64 + slotb;
#pragma unroll
  for (int jj = 0; jj < 4; ++jj)
    bOff[jj] = (wc + jj * 16 + (lane & 15)) * 64 + slotb;

  const int nt = (int)(K >> 5);

  auto STAGE_A = [&](int buf, int t) {
    const long koff = (long)t << 5;
#pragma unroll
    for (int j = 0; j < 2; ++j)
      gload16(aS + koff + (long)j * 128 * lda, &ldsA[buf][j * 8192 + ldst]);
  };
  auto STAGE_B = [&](int buf, int t) {
    const long koff = (long)t << 5;
#pragma unroll
    for (int j = 0; j < 2; ++j)
      gload16(bS + koff + (long)j * 128 * K, &ldsB[buf][j * 8192 + ldst]);
  };

  STAGE_A(0, 0); STAGE_B(0, 0);
  STAGE_A(1, 1); STAGE_B(1, 1);
  int cur = 0, stg = 2;
  for (int t = 0; t < nt; ++t) {
    // my 4 loads for tile t landed (tile t+1's 4 stay in flight); then barrier
    // so ALL waves' tile-t writes are visible before any wave reads.
    if (t < nt - 1) { WAITVM(4); } else { WAITVM(0); }
    SBAR();
    const bool doStage = (t + 2 < nt);
    bf16x8 bfr[4], af[4];
    // ---- phase 0: B frags + A rows 0..63, stage next A half ----
#pragma unroll
    for (int jj = 0; jj < 4; ++jj) bfr[jj] = *(const bf16x8*)(&ldsB[cur][bOff[jj]]);
#pragma unroll
    for (int ii = 0; ii < 4; ++ii) af[ii] = *(const bf16x8*)(&ldsA[cur][aOff[ii]]);
    if (doStage) STAGE_A(stg, t + 2);
    SBAR();
    __builtin_amdgcn_s_setprio(1);
#pragma unroll
    for (int ii = 0; ii < 4; ++ii)
#pragma unroll
      for (int jj = 0; jj < 4; ++jj)
        acc[ii][jj] = __builtin_amdgcn_mfma_f32_16x16x32_bf16(af[ii], bfr[jj], acc[ii][jj], 0, 0, 0);
    __builtin_amdgcn_s_setprio(0);
    SBAR();
    // ---- phase 1: A rows 64..127 (B frags reused), stage next B half ----
#pragma unroll
    for (int ii = 0; ii < 4; ++ii) af[ii] = *(const bf16x8*)(&ldsA[cur][aOff[4 + ii]]);
    if (doStage) STAGE_B(stg, t + 2);
    SBAR();
    __builtin_amdgcn_s_setprio(1);
#pragma unroll
    for (int ii = 0; ii < 4; ++ii)
#pragma unroll
      for (int jj = 0; jj < 4; ++jj)
        acc[4 + ii][jj] = __builtin_amdgcn_mfma_f32_16x16x32_bf16(af[ii], bfr[jj], acc[4 + ii][jj], 0, 0, 0);
    __builtin_amdgcn_s_setprio(0);
    cur = (cur == 2) ? 0 : cur + 1;
    stg = (stg == 2) ? 0 : stg + 1;
  }

  // epilogue: C/D layout col=lane&15, row=(lane>>4)*4+r
  const int orow = (lane >> 4) * 4;
  const int ocol = lane & 15;
#pragma unroll
  for (int i = 0; i < 8; ++i) {
    const long gr0 = row0 + wr + i * 16 + orow;
#pragma unroll
    for (int j = 0; j < 4; ++j) {
      const long gc = col0 + wc + j * 16 + ocol;
      const float bb = bias[gc];
#pragma unroll
      for (int r = 0; r < 4; ++r) {
        const long gr = gr0 + r;
        float v = acc[i][j][r] + bb;
        if (RESID == 1) {
          // residual = x in bf16, already resident as A-panel cols 0..2047
          unsigned short us = A[gr * lda + gc];
          v += __uint_as_float(((unsigned)us) << 16);
        }
        out[gr * ldo + gc] = v;
      }
    }
  }
}

// ---------------- blocked linear scan over T ----------------
__global__ void scan_local_kernel(const float* __restrict__ v, float* __restrict__ s_loc,
                                  const float* __restrict__ td) {
  const int m = threadIdx.x;   // 512
  const int c = blockIdx.x;    // chunk
  const int b = blockIdx.y;
  const float decay = sigm(td[m]) * 0.9f + 0.1f;
  const float* vp = v + ((size_t)b * TT + (size_t)c * CHUNK) * MDIM + m;
  float s = 0.f;
#pragma unroll 8
  for (int t = 0; t < CHUNK; ++t) s = s * decay + vp[(size_t)t * MDIM];
  s_loc[((size_t)b * NCH + c) * MDIM + m] = s;
}

__global__ void scan_chunks_kernel(const float* __restrict__ s_loc, const float* __restrict__ mem0,
                                   float* __restrict__ s_in, float* __restrict__ nextmem,
                                   const float* __restrict__ td) {
  const int m = threadIdx.x;
  const int b = blockIdx.x;
  const float decay = sigm(td[m]) * 0.9f + 0.1f;
  const float d2 = decay * decay, d4 = d2 * d2, d8 = d4 * d4;
  const float d16 = d8 * d8, d32 = d16 * d16, dL = d32 * d32;  // decay^64
  float s = mem0[(size_t)b * MDIM + m];
  for (int c = 0; c < NCH; ++c) {
    const size_t idx = ((size_t)b * NCH + c) * MDIM + m;
    s_in[idx] = s;
    s = s * dL + s_loc[idx];
  }
  nextmem[(size_t)b * MDIM + m] = s;
}

__global__ void scan_replay_kernel(const float* __restrict__ v, const float* __restrict__ s_in,
                                   unsigned short* __restrict__ comb,
                                   const float* __restrict__ td, const float* __restrict__ tf) {
  const int m = threadIdx.x;
  const int c = blockIdx.x;
  const int b = blockIdx.y;
  const float decay = sigm(td[m]) * 0.9f + 0.1f;
  const float first = sigm(tf[m]);
  float s = s_in[((size_t)b * NCH + c) * MDIM + m];
  const float* vp = v + ((size_t)b * TT + (size_t)c * CHUNK) * MDIM + m;
  unsigned short* wp = comb + ((size_t)b * TT + (size_t)c * CHUNK) * KCAT + DDIM + m;
#pragma unroll 4
  for (int t = 0; t < CHUNK; ++t) {
    const float vv = vp[(size_t)t * MDIM];
    wp[(size_t)t * KCAT] = f2bf(vv + s * first);
    s = s * decay + vv;
  }
}

extern "C" void kernel_launch(void* const* d_in, const int* in_sizes, int n_in,
                              void* d_out, int out_size, void* d_ws, size_t ws_size,
                              hipStream_t stream) {
  const float* x    = (const float*)d_in[0];
  const float* mem0 = (const float*)d_in[1];
  const float* Wv   = (const float*)d_in[2];
  const float* bv   = (const float*)d_in[3];
  const float* Wg   = (const float*)d_in[4];
  const float* bg   = (const float*)d_in[5];
  const float* td   = (const float*)d_in[6];
  const float* tf   = (const float*)d_in[7];

  float* out = (float*)d_out;
  float* nextmem = out + (size_t)NROWS * DDIM;
  float* vbuf = out;  // v scratch lives in d_out; GEMM2 overwrites it at the end

  // workspace layout (~93 MB total)
  unsigned short* comb = (unsigned short*)d_ws;                 // [16384][2560] bf16
  unsigned short* WvB  = comb + (size_t)NROWS * KCAT;           // [512][2048] bf16
  unsigned short* WgB  = WvB + (size_t)MDIM * DDIM;             // [2048][2560] bf16
  float* s_loc = (float*)(WgB + (size_t)DDIM * KCAT);           // [4][64][512] f32
  float* s_in  = s_loc + (size_t)BB * NCH * MDIM;               // [4][64][512] f32

  cvt_x_kernel<<<(NROWS * DDIM / 4) / 256, 256, 0, stream>>>(x, comb);
  cvt_w_kernel<<<(MDIM * DDIM / 4) / 256, 256, 0, stream>>>(Wv, WvB, (long)MDIM * DDIM / 4);
  cvt_w_kernel<<<(DDIM * KCAT / 4) / 256, 256, 0, stream>>>(Wg, WgB, (long)DDIM * KCAT / 4);

  // GEMM1: v = x_bf16 (lda=KCAT, first 2048 cols) @ Wv^T + bv -> vbuf f32 [16384,512]
  gemm_bf16_kernel<0><<<(NROWS / 128) * (MDIM / 128), 256, 0, stream>>>(
      comb, KCAT, WvB, DDIM, vbuf, MDIM, bv, nullptr, MDIM / 128);

  scan_local_kernel<<<dim3(NCH, BB), MDIM, 0, stream>>>(vbuf, s_loc, td);
  scan_chunks_kernel<<<BB, MDIM, 0, stream>>>(s_loc, mem0, s_in, nextmem, td);
  scan_replay_kernel<<<dim3(NCH, BB), MDIM, 0, stream>>>(vbuf, s_in, comb, td, tf);

  // GEMM2: out = x_bf16 + combined @ Wg^T + bg -> d_out f32 [16384,2048]
  gemm256_kernel<1><<<(NROWS / 256) * (DDIM / 256), 512, 0, stream>>>(
      comb, KCAT, WgB, KCAT, out, DDIM, bg, DDIM / 256);
}